// Round 17
// baseline (381.501 us; speedup 1.0000x reference)
//
#include <hip/hip_runtime.h>
#include <hip/hip_bf16.h>
#include <math.h>

#define IMG 1024
#define NPIXTOT (IMG * IMG)
#define TWO_PI_F 6.28318530717958647692f
#define CHUNKS 4                       // 4 x 256 px per block: stage once, loop chunks

typedef __attribute__((ext_vector_type(8))) short short8;
typedef __attribute__((ext_vector_type(4))) float f32x4;
typedef unsigned int uint;
typedef unsigned short ushort;

// bf16 weight image (W^T) + LUTs in d_ws; staged whole into LDS ONCE per block,
// then a barrier-free chunk loop (LDS is read-only after staging).
// Per layer: tile t = nt*KS+ks, element (t*512 + (hi*16+lo)*8 + i) <->
// A[m = nt*16+lo][k' = ks*32+hi*8+i]. L1 k'-axis carries the in-lane feature
// permutation (R7); L2..4 k-axis permuted by permM so producer D == consumer B.
#define A1_OFF 0        // L1: NT=4, KS=4
#define A2_OFF 8192     // L2: NT=8, KS=2
#define A3_OFF 16384    // L3: NT=4, KS=4
#define A4_OFF 24576    // L4: NT=1, KS=2 (m 4->16 zero-pad)
#define WTOT   25600
#define GLUT_N    2304  // gelu [-4,5), h=1/256; entry j = bf16(gelu((j-1024)/256))
#define GLUTA_OFF 25600
#define GLUTB_OFF 27904 // second copy (lanes 32-63)
#define SLUT_OFF  30208 // 1024 x uint: lo=bf16(sin 2pi k/1024), hi=bf16(sin 4pi k/1024)
#define SLUT_N    2048  // ushorts
#define WSTOT     32256 // ushorts = 64,512 B (<= 64 KiB static) -> 2 blocks/CU

#define LATBF_BYTEOFF 65536            // bf16 latent image location in d_ws

__device__ __forceinline__ ushort f2bf(float f) {   // RNE f32->bf16
    uint u = __float_as_uint(f);
    u += 0x7fffu + ((u >> 16) & 1u);
    return (ushort)(u >> 16);
}
__device__ __forceinline__ uint pack2(float a, float b) {  // v_cvt_pk_bf16_f32
    float2 t; t.x = a; t.y = b;
    __hip_bfloat162 h = __float22bfloat162_rn(t);
    union { __hip_bfloat162 h; uint u; } cv; cv.h = h;
    return cv.u;
}
__device__ __forceinline__ float sig_fast(float x) {
    return __builtin_amdgcn_rcpf(1.0f + __expf(-x));
}

// Two GELU lookups merged into one uint. Index round(x*256)+1024 clamped to
// [0,2303] = domain [-4,5). Proven bit-identical: R13/R15/R16 all held absmax
// at 0.00390625; |gelu(x<-4)| <= 1.3e-4.
__device__ __forceinline__ uint gelu2(float x0, float x1, const ushort* g) {
    union { uint u; ushort h[2]; } w;
    w.h[0] = g[(int)__builtin_amdgcn_fmed3f(fmaf(x0, 256.0f, 1024.5f), 0.0f, 2303.0f)];
    w.h[1] = g[(int)__builtin_amdgcn_fmed3f(fmaf(x1, 256.0f, 1024.5f), 0.0f, 2303.0f)];
    return w.u;
}

// producer-neuron index feeding consumer k-position k (layers 2..4)
__device__ __forceinline__ int permM(int k) {
    return (2 * (k >> 5) + ((k >> 2) & 1)) * 16 + 4 * ((k >> 3) & 3) + (k & 3);
}

// clamped coords of neighbor n for pixel at rp
__device__ __forceinline__ int2 nbc(int2 rp, int n) {
    const int dxi = (n * 86) >> 8;     // n/3 for n<9
    int2 c;
    c.x = min(max(rp.x + dxi - 1, 0), IMG - 1);
    c.y = min(max(rp.y + (n - 3 * dxi) - 1, 0), IMG - 1);
    return c;
}

__global__ void prep_weights(const float* __restrict__ W1, const float* __restrict__ b1,
                             const float* __restrict__ W2, const float* __restrict__ W3,
                             const float* __restrict__ W4, ushort* __restrict__ ws) {
    int e = blockIdx.x * 256 + threadIdx.x;
    if (e >= WSTOT) return;
    float v;
    if (e < A2_OFF) {                       // L1 with the in-lane feature permutation
        int i = e & 7, lo = (e >> 3) & 15, hi = (e >> 7) & 3, kst = e >> 9;
        int ks = kst & 3;
        int m = (kst >> 2) * 16 + lo;
        int korig;                          // original feature index, 999 = zero pad
        if (ks < 2)       korig = 12 * (2 * hi + ks) + i;                  // nb f0..7
        else if (ks == 2) korig = 12 * (2 * hi + (i >> 2)) + 8 + (i & 3);  // S2+ctrl pairs
        else {   // ks == 3
            if (hi == 0)      korig = 96 + i;                              // nb8 f0..7
            else if (hi == 1) korig = (i < 4) ? 104 + i : (i == 4 ? 108 : 999);
            else              korig = 999;
        }
        v = (korig < 108) ? W1[korig * 64 + m] : (korig == 108 ? b1[m] : 0.0f);
    } else if (e < A3_OFF) {                // L2: K=64 permuted
        int r = e - A2_OFF, i = r & 7, lo = (r >> 3) & 15, hi = (r >> 7) & 3, kst = r >> 9;
        int m = (kst >> 1) * 16 + lo, k = (kst & 1) * 32 + hi * 8 + i;
        v = W2[permM(k) * 128 + m];
    } else if (e < A4_OFF) {                // L3: K=128 permuted
        int r = e - A3_OFF, i = r & 7, lo = (r >> 3) & 15, hi = (r >> 7) & 3, kst = r >> 9;
        int m = (kst >> 2) * 16 + lo, k = (kst & 3) * 32 + hi * 8 + i;
        v = W3[permM(k) * 64 + m];
    } else if (e < GLUTA_OFF) {             // L4: K=64 permuted, m padded 4->16
        int r = e - A4_OFF, i = r & 7, lo = (r >> 3) & 15, hi = (r >> 7) & 3, ks = (r >> 9) & 1;
        int k = ks * 32 + hi * 8 + i;
        v = (lo < 4) ? W4[permM(k) * 4 + lo] : 0.0f;
    } else if (e < GLUTB_OFF) {             // GELU table copy A [-4,5)
        const float x = (float)(e - GLUTA_OFF - 1024) * (1.0f / 256.0f);
        v = 0.5f * x * (1.0f + erff(x * 0.70710678118654752440f));
    } else if (e < SLUT_OFF) {              // GELU table copy B (identical)
        const float x = (float)(e - GLUTB_OFF - 1024) * (1.0f / 256.0f);
        v = 0.5f * x * (1.0f + erff(x * 0.70710678118654752440f));
    } else {                                // sin table: even j -> sin(2pi), odd -> sin(4pi)
        const int j = e - SLUT_OFF;
        const float a = (float)(j >> 1) * (1.0f / 1024.0f);
        v = sinf(((j & 1) ? 2.0f : 1.0f) * TWO_PI_F * a);
    }
    ws[e] = f2bf(v);
}

__global__ void prep_latent(const float* __restrict__ lat, ushort* __restrict__ dst) {
    const int i = blockIdx.x * 256 + threadIdx.x;   // one float4 -> 4 bf16
    if (i >= NPIXTOT) return;
    const float4 v = ((const float4*)lat)[i];
    union { ushort h[4]; uint2 u; } o;
    o.h[0] = f2bf(v.x); o.h[1] = f2bf(v.y); o.h[2] = f2bf(v.z); o.h[3] = f2bf(v.w);
    ((uint2*)dst)[i] = o.u;
}

// One layer fully in registers with double-buffered A-fragment prefetch (R14).
// GELU via direct bf16 LDS lookup. All indices compile-time under full unroll.
template<int KS, int KSN, bool HASB>
__device__ __forceinline__ void mlayer_pf(const short8 (&bin)[2][KS], short8 (&bout)[2][KSN],
                                          const ushort* wA,
                                          const float* __restrict__ bias,
                                          const ushort* gl, int lo, int hi) {
    const int lane8 = (hi * 16 + lo) * 8;
    short8 a[2][2 * KS];                 // double buffer: [kn&1][b*KS+ks]
    #pragma unroll
    for (int t = 0; t < 2 * KS; ++t)
        a[0][t] = *(const short8*)&wA[t * 512 + lane8];

    #pragma unroll
    for (int kn = 0; kn < KSN; ++kn) {
        if (kn + 1 < KSN) {
            #pragma unroll
            for (int t = 0; t < 2 * KS; ++t)
                a[(kn + 1) & 1][t] =
                    *(const short8*)&wA[((kn + 1) * 2 * KS + t) * 512 + lane8];
        }
        f32x4 acc[2][2];   // [b = nt parity][pixel tile]
        #pragma unroll
        for (int b = 0; b < 2; ++b) {
            if (HASB) {
                const float4 bv = *(const float4*)&bias[(2 * kn + b) * 16 + hi * 4];
                acc[b][0] = f32x4{bv.x, bv.y, bv.z, bv.w};
            } else {
                acc[b][0] = f32x4{0.f, 0.f, 0.f, 0.f};
            }
            acc[b][1] = acc[b][0];
            #pragma unroll
            for (int ks = 0; ks < KS; ++ks) {
                const short8 av = a[kn & 1][b * KS + ks];
                acc[b][0] = __builtin_amdgcn_mfma_f32_16x16x32_bf16(av, bin[0][ks], acc[b][0], 0, 0, 0);
                acc[b][1] = __builtin_amdgcn_mfma_f32_16x16x32_bf16(av, bin[1][ks], acc[b][1], 0, 0, 0);
            }
        }
        #pragma unroll
        for (int pt = 0; pt < 2; ++pt) {
            union { short8 s; uint u[4]; } o;
            o.u[0] = gelu2(acc[0][pt][0], acc[0][pt][1], gl);
            o.u[1] = gelu2(acc[0][pt][2], acc[0][pt][3], gl);
            o.u[2] = gelu2(acc[1][pt][0], acc[1][pt][1], gl);
            o.u[3] = gelu2(acc[1][pt][2], acc[1][pt][3], gl);
            bout[pt][kn] = o.s;
        }
    }
}

// __launch_bounds__(512, 4): 2 blocks/CU target, VGPR cap 128 >> natural 52.
// Do NOT raise the 2nd arg (R11/R15: VGPR squeeze = -20% to -75%).
template<bool BF>
__global__ __launch_bounds__(512, 4) void vfx_mfma(
    const float* __restrict__ latent, const uint2* __restrict__ latbf,
    const int* __restrict__ raw_pos, const float* __restrict__ control,
    const ushort* __restrict__ wsrc,
    const float* __restrict__ b2, const float* __restrict__ b3,
    const float* __restrict__ b4, float* __restrict__ out)
{
    __shared__ ushort wl[WSTOT];            // 64,512 B -> 2 blocks/CU (16 waves)
    const int tid = threadIdx.x;
    const int wave = tid >> 6, lane = tid & 63;
    const int lo = lane & 15, hi = lane >> 4;
    const int blockBase = blockIdx.x * (CHUNKS * 256);

    {   // stage weights + LUTs ONCE per block: 4032 uint4
        const uint4* src = (const uint4*)wsrc;
        uint4* dst = (uint4*)wl;
        #pragma unroll
        for (int it = 0; it < 8; ++it) {
            const int i = tid + it * 512;
            if (i < WSTOT / 8) dst[i] = src[i];
        }
    }
    __syncthreads();   // LDS image ready; read-only from here: NO more barriers
    const ushort* glut = wl + (GLUTA_OFF + ((lane & 32) ? (GLUTB_OFF - GLUTA_OFF) : 0));
    const uint*   slut = (const uint*)(wl + SLUT_OFF);

    #pragma unroll 1   // keep loop body = R16's straight-line code (no pressure growth)
    for (int c = 0; c < CHUNKS; ++c) {
        const int pixbase = blockBase + c * 256 + wave * 32;

        // ---- positional data + latent gathers for this chunk ----
        const int g0 = pixbase + lo, g1 = pixbase + 16 + lo;
        const int2 rp0 = ((const int2*)raw_pos)[g0];
        const int2 rp1 = ((const int2*)raw_pos)[g1];
        const float2 cf0 = ((const float2*)control)[g0];
        const float2 cf1 = ((const float2*)control)[g1];

        const int na = 2 * hi, nbb = 2 * hi + 1;
        const int2 cA0 = nbc(rp0, na), cB0 = nbc(rp0, nbb);
        const int2 cA1 = nbc(rp1, na), cB1 = nbc(rp1, nbb);
        const int2 c80 = nbc(rp0, 8),  c81 = nbc(rp1, 8);

        uint2 lA0, lB0, lA1, lB1, l80, l81;
        if (BF) {
            lA0 = latbf[(cA0.y << 10) + cA0.x]; lB0 = latbf[(cB0.y << 10) + cB0.x];
            lA1 = latbf[(cA1.y << 10) + cA1.x]; lB1 = latbf[(cB1.y << 10) + cB1.x];
            if (hi == 0) { l80 = latbf[(c80.y << 10) + c80.x]; l81 = latbf[(c81.y << 10) + c81.x]; }
        } else {
            const float4* lf = (const float4*)latent;
            float4 a;
            a = lf[(cA0.y << 10) + cA0.x]; lA0 = make_uint2(pack2(a.x, a.y), pack2(a.z, a.w));
            a = lf[(cB0.y << 10) + cB0.x]; lB0 = make_uint2(pack2(a.x, a.y), pack2(a.z, a.w));
            a = lf[(cA1.y << 10) + cA1.x]; lA1 = make_uint2(pack2(a.x, a.y), pack2(a.z, a.w));
            a = lf[(cB1.y << 10) + cB1.x]; lB1 = make_uint2(pack2(a.x, a.y), pack2(a.z, a.w));
            if (hi == 0) {
                a = lf[(c80.y << 10) + c80.x]; l80 = make_uint2(pack2(a.x, a.y), pack2(a.z, a.w));
                a = lf[(c81.y << 10) + c81.x]; l81 = make_uint2(pack2(a.x, a.y), pack2(a.z, a.w));
            }
        }

        // ---- assemble L1 B-fragments in registers (permuted feature order) ----
        short8 bX[2][4];
        {
            auto mk = [&](int2 cc, uint2 lat, uint& s2u) -> short8 {
                const uint sx = slut[cc.x], sy = slut[cc.y];
                s2u = (sx >> 16) | (sy & 0xffff0000u);
                union { short8 s; uint u[4]; } o;
                o.u[0] = lat.x; o.u[1] = lat.y;
                o.u[2] = pack2((float)cc.x * (1.0f / IMG), (float)cc.y * (1.0f / IMG));
                o.u[3] = (sx & 0xffffu) | (sy << 16);
                return o.s;
            };
            uint s2a0, s2b0, s2a1, s2b1;
            bX[0][0] = mk(cA0, lA0, s2a0);
            bX[0][1] = mk(cB0, lB0, s2b0);
            bX[1][0] = mk(cA1, lA1, s2a1);
            bX[1][1] = mk(cB1, lB1, s2b1);
            const uint upc0 = pack2(cf0.x, cf0.y), upc1 = pack2(cf1.x, cf1.y);
            union { short8 s; uint u[4]; } t;
            t.u[0] = s2a0; t.u[1] = upc0; t.u[2] = s2b0; t.u[3] = upc0; bX[0][2] = t.s;
            t.u[0] = s2a1; t.u[1] = upc1; t.u[2] = s2b1; t.u[3] = upc1; bX[1][2] = t.s;
            if (hi == 0) {          // S1 frag of neighbor 8
                uint d0, d1;
                bX[0][3] = mk(c80, l80, d0);
                bX[1][3] = mk(c81, l81, d1);
            } else if (hi == 1) {   // [s2(nb8), ctrl, 1.0(bias), 0...]
                union { short8 s; uint u[4]; } o;
                o.u[0] = (slut[c80.x] >> 16) | (slut[c80.y] & 0xffff0000u);
                o.u[1] = upc0; o.u[2] = 0x3f80u; o.u[3] = 0u;
                bX[0][3] = o.s;
                o.u[0] = (slut[c81.x] >> 16) | (slut[c81.y] & 0xffff0000u);
                o.u[1] = upc1;
                bX[1][3] = o.s;
            } else {
                union { short8 s; uint u[4]; } z;
                z.u[0] = 0u; z.u[1] = 0u; z.u[2] = 0u; z.u[3] = 0u;
                bX[0][3] = z.s; bX[1][3] = z.s;
            }
        }

        short8 h1[2][2], h2[2][4], h3[2][2];
        mlayer_pf<4, 2, false>(bX, h1, wl + A1_OFF, nullptr, glut, lo, hi);  // 128 -> 64
        mlayer_pf<2, 4, true >(h1, h2, wl + A2_OFF, b2, glut, lo, hi);       // 64  -> 128
        mlayer_pf<4, 2, true >(h2, h3, wl + A3_OFF, b3, glut, lo, hi);       // 128 -> 64

        // ---- L4: 64 -> 4 (m-padded 16), sigmoid, float4 store ----
        {
            float4 bv = {0.f, 0.f, 0.f, 0.f};
            if (hi == 0) bv = *(const float4*)b4;
            f32x4 acc0 = {bv.x, bv.y, bv.z, bv.w};
            f32x4 acc1 = acc0;
            #pragma unroll
            for (int ks = 0; ks < 2; ++ks) {
                const short8 a = *(const short8*)&wl[A4_OFF + (ks * 512) + (hi * 16 + lo) * 8];
                acc0 = __builtin_amdgcn_mfma_f32_16x16x32_bf16(a, h3[0][ks], acc0, 0, 0, 0);
                acc1 = __builtin_amdgcn_mfma_f32_16x16x32_bf16(a, h3[1][ks], acc1, 0, 0, 0);
            }
            if (hi == 0) {   // rows 0..3 = the 4 outputs, col = pixel lo
                float4 o;
                o.x = sig_fast(acc0[0]); o.y = sig_fast(acc0[1]);
                o.z = sig_fast(acc0[2]); o.w = sig_fast(acc0[3]);
                *(float4*)&out[(pixbase + lo) * 4] = o;
                o.x = sig_fast(acc1[0]); o.y = sig_fast(acc1[1]);
                o.z = sig_fast(acc1[2]); o.w = sig_fast(acc1[3]);
                *(float4*)&out[(pixbase + 16 + lo) * 4] = o;
            }
        }
    }
}

extern "C" void kernel_launch(void* const* d_in, const int* in_sizes, int n_in,
                              void* d_out, int out_size, void* d_ws, size_t ws_size,
                              hipStream_t stream) {
    const float* latent  = (const float*)d_in[0];
    const int*   raw_pos = (const int*)  d_in[1];
    const float* control = (const float*)d_in[2];
    const float* W1 = (const float*)d_in[3];
    const float* b1 = (const float*)d_in[4];
    const float* W2 = (const float*)d_in[5];
    const float* b2 = (const float*)d_in[6];
    const float* W3 = (const float*)d_in[7];
    const float* b3 = (const float*)d_in[8];
    const float* W4 = (const float*)d_in[9];
    const float* b4 = (const float*)d_in[10];
    float* out = (float*)d_out;
    ushort* ws = (ushort*)d_ws;

    prep_weights<<<dim3((WSTOT + 255) / 256), dim3(256), 0, stream>>>(W1, b1, W2, W3, W4, ws);

    const size_t need = (size_t)LATBF_BYTEOFF + (size_t)NPIXTOT * 8;
    const bool use_bf = ws_size >= need;
    dim3 grid(NPIXTOT / (CHUNKS * 256));   // 1024 blocks x 512 threads, 1024 px/block

    if (use_bf) {
        ushort* latbf = (ushort*)((char*)d_ws + LATBF_BYTEOFF);
        prep_latent<<<dim3(NPIXTOT / 256), dim3(256), 0, stream>>>(latent, latbf);
        vfx_mfma<true><<<grid, dim3(512), 0, stream>>>(
            latent, (const uint2*)latbf, raw_pos, control, ws, b2, b3, b4, out);
    } else {
        vfx_mfma<false><<<grid, dim3(512), 0, stream>>>(
            latent, nullptr, raw_pos, control, ws, b2, b3, b4, out);
    }
}

// Round 18
// 95.771 us; speedup vs baseline: 3.9835x; 3.9835x over previous
//
#include <hip/hip_runtime.h>
#include <hip/hip_bf16.h>
#include <math.h>

#define IMG 1024
#define NPIXTOT (IMG * IMG)
#define TWO_PI_F 6.28318530717958647692f

typedef __attribute__((ext_vector_type(8))) short short8;
typedef __attribute__((ext_vector_type(4))) float f32x4;
typedef unsigned int uint;
typedef unsigned short ushort;

// bf16 weight image (W^T) + LUTs in d_ws; staged whole into LDS per block.
// Per layer: tile t = nt*KS+ks, element (t*512 + (hi*16+lo)*8 + i) <->
// A[m = nt*16+lo][k' = ks*32+hi*8+i]. L1 k'-axis carries the in-lane feature
// permutation (R7); L2..4 k-axis permuted by permM so producer D == consumer B.
#define A1_OFF 0        // L1: NT=4, KS=4
#define A2_OFF 8192     // L2: NT=8, KS=2
#define A3_OFF 16384    // L3: NT=4, KS=4
#define A4_OFF 24576    // L4: NT=1, KS=2 (m 4->16 zero-pad)
#define WTOT   25600
#define GLUT_N   3072   // gelu [-6,6), h=1/256; entry i = bf16(gelu((i-1536)/256))
#define GLUT_OFF WTOT
#define SLUT_OFF (GLUT_OFF + GLUT_N)   // 1024 x uint: lo=bf16(sin 2pi k/1024), hi=bf16(sin 4pi k/1024)
#define SLUT_N   2048                  // ushorts
#define WSTOT    (SLUT_OFF + SLUT_N)   // 30720 ushorts = 61,440 B = 3840 uint4

#define LATBF_BYTEOFF 65536            // bf16 latent image location in d_ws

__device__ __forceinline__ ushort f2bf(float f) {   // RNE f32->bf16
    uint u = __float_as_uint(f);
    u += 0x7fffu + ((u >> 16) & 1u);
    return (ushort)(u >> 16);
}
__device__ __forceinline__ uint pack2(float a, float b) {  // v_cvt_pk_bf16_f32
    float2 t; t.x = a; t.y = b;
    __hip_bfloat162 h = __float22bfloat162_rn(t);
    union { __hip_bfloat162 h; uint u; } cv; cv.h = h;
    return cv.u;
}
__device__ __forceinline__ float sig_fast(float x) {
    return __builtin_amdgcn_rcpf(1.0f + __expf(-x));
}

// Two GELU lookups merged into one uint (ds_read_u16 + ds_read_u16_d16_hi).
__device__ __forceinline__ uint gelu2(float x0, float x1, const ushort* g) {
    union { uint u; ushort h[2]; } w;
    w.h[0] = g[(int)__builtin_amdgcn_fmed3f(fmaf(x0, 256.0f, 1536.5f), 0.0f, 3071.0f)];
    w.h[1] = g[(int)__builtin_amdgcn_fmed3f(fmaf(x1, 256.0f, 1536.5f), 0.0f, 3071.0f)];
    return w.u;
}

// producer-neuron index feeding consumer k-position k (layers 2..4)
__device__ __forceinline__ int permM(int k) {
    return (2 * (k >> 5) + ((k >> 2) & 1)) * 16 + 4 * ((k >> 3) & 3) + (k & 3);
}

// clamped coords of neighbor n for pixel at rp
__device__ __forceinline__ int2 nbc(int2 rp, int n) {
    const int dxi = (n * 86) >> 8;     // n/3 for n<9
    int2 c;
    c.x = min(max(rp.x + dxi - 1, 0), IMG - 1);
    c.y = min(max(rp.y + (n - 3 * dxi) - 1, 0), IMG - 1);
    return c;
}

// Fused prep: weight/LUT image (e < WSTOT) + bf16 latent conversion (all 1M).
__global__ void prep_all(const float* __restrict__ W1, const float* __restrict__ b1,
                         const float* __restrict__ W2, const float* __restrict__ W3,
                         const float* __restrict__ W4, const float* __restrict__ lat,
                         ushort* __restrict__ ws, ushort* __restrict__ latbf) {
    const int e = blockIdx.x * 256 + threadIdx.x;

    if (e < WSTOT) {
        float v;
        if (e < A2_OFF) {                       // L1 with the in-lane feature permutation
            int i = e & 7, lo = (e >> 3) & 15, hi = (e >> 7) & 3, kst = e >> 9;
            int ks = kst & 3;
            int m = (kst >> 2) * 16 + lo;
            int korig;                          // original feature index, 999 = zero pad
            if (ks < 2)       korig = 12 * (2 * hi + ks) + i;                  // nb f0..7
            else if (ks == 2) korig = 12 * (2 * hi + (i >> 2)) + 8 + (i & 3);  // S2+ctrl pairs
            else {   // ks == 3
                if (hi == 0)      korig = 96 + i;                              // nb8 f0..7
                else if (hi == 1) korig = (i < 4) ? 104 + i : (i == 4 ? 108 : 999);
                else              korig = 999;
            }
            v = (korig < 108) ? W1[korig * 64 + m] : (korig == 108 ? b1[m] : 0.0f);
        } else if (e < A3_OFF) {                // L2: K=64 permuted
            int r = e - A2_OFF, i = r & 7, lo = (r >> 3) & 15, hi = (r >> 7) & 3, kst = r >> 9;
            int m = (kst >> 1) * 16 + lo, k = (kst & 1) * 32 + hi * 8 + i;
            v = W2[permM(k) * 128 + m];
        } else if (e < A4_OFF) {                // L3: K=128 permuted
            int r = e - A3_OFF, i = r & 7, lo = (r >> 3) & 15, hi = (r >> 7) & 3, kst = r >> 9;
            int m = (kst >> 2) * 16 + lo, k = (kst & 3) * 32 + hi * 8 + i;
            v = W3[permM(k) * 64 + m];
        } else if (e < GLUT_OFF) {              // L4: K=64 permuted, m padded 4->16
            int r = e - A4_OFF, i = r & 7, lo = (r >> 3) & 15, hi = (r >> 7) & 3, ks = (r >> 9) & 1;
            int k = ks * 32 + hi * 8 + i;
            v = (lo < 4) ? W4[permM(k) * 4 + lo] : 0.0f;
        } else if (e < SLUT_OFF) {              // GELU table
            const float x = (float)(e - GLUT_OFF - 1536) * (1.0f / 256.0f);
            v = 0.5f * x * (1.0f + erff(x * 0.70710678118654752440f));
        } else {                                // sin table: even j -> sin(2pi), odd -> sin(4pi)
            const int j = e - SLUT_OFF;
            const float a = (float)(j >> 1) * (1.0f / 1024.0f);
            v = sinf(((j & 1) ? 2.0f : 1.0f) * TWO_PI_F * a);
        }
        ws[e] = f2bf(v);
    }

    if (e < NPIXTOT) {                          // latent f32x4 -> bf16x4
        const float4 v4 = ((const float4*)lat)[e];
        union { ushort h[4]; uint2 u; } o;
        o.h[0] = f2bf(v4.x); o.h[1] = f2bf(v4.y); o.h[2] = f2bf(v4.z); o.h[3] = f2bf(v4.w);
        ((uint2*)latbf)[e] = o.u;
    }
}

// One layer fully in registers with double-buffered A-fragment prefetch (R14).
// GELU via direct bf16 LDS lookup. All indices compile-time under full unroll.
template<int KS, int KSN, bool HASB>
__device__ __forceinline__ void mlayer_pf(const short8 (&bin)[2][KS], short8 (&bout)[2][KSN],
                                          const ushort* wA,
                                          const float* __restrict__ bias,
                                          const ushort* gl, int lo, int hi) {
    const int lane8 = (hi * 16 + lo) * 8;
    short8 a[2][2 * KS];                 // double buffer: [kn&1][b*KS+ks]
    #pragma unroll
    for (int t = 0; t < 2 * KS; ++t)
        a[0][t] = *(const short8*)&wA[t * 512 + lane8];

    #pragma unroll
    for (int kn = 0; kn < KSN; ++kn) {
        if (kn + 1 < KSN) {
            #pragma unroll
            for (int t = 0; t < 2 * KS; ++t)
                a[(kn + 1) & 1][t] =
                    *(const short8*)&wA[((kn + 1) * 2 * KS + t) * 512 + lane8];
        }
        f32x4 acc[2][2];   // [b = nt parity][pixel tile]
        #pragma unroll
        for (int b = 0; b < 2; ++b) {
            if (HASB) {
                const float4 bv = *(const float4*)&bias[(2 * kn + b) * 16 + hi * 4];
                acc[b][0] = f32x4{bv.x, bv.y, bv.z, bv.w};
            } else {
                acc[b][0] = f32x4{0.f, 0.f, 0.f, 0.f};
            }
            acc[b][1] = acc[b][0];
            #pragma unroll
            for (int ks = 0; ks < KS; ++ks) {
                const short8 av = a[kn & 1][b * KS + ks];
                acc[b][0] = __builtin_amdgcn_mfma_f32_16x16x32_bf16(av, bin[0][ks], acc[b][0], 0, 0, 0);
                acc[b][1] = __builtin_amdgcn_mfma_f32_16x16x32_bf16(av, bin[1][ks], acc[b][1], 0, 0, 0);
            }
        }
        #pragma unroll
        for (int pt = 0; pt < 2; ++pt) {
            union { short8 s; uint u[4]; } o;
            o.u[0] = gelu2(acc[0][pt][0], acc[0][pt][1], gl);
            o.u[1] = gelu2(acc[0][pt][2], acc[0][pt][3], gl);
            o.u[2] = gelu2(acc[1][pt][0], acc[1][pt][1], gl);
            o.u[3] = gelu2(acc[1][pt][2], acc[1][pt][3], gl);
            bout[pt][kn] = o.s;
        }
    }
}

// __launch_bounds__(512, 4): 2 blocks/CU, VGPR cap 128 >> natural 52.
// Do NOT restructure: R10/R11/R12/R13/R15/R17 all broke the 52-VGPR schedule
// (squeeze or spill) and lost 20-300%. This shape is the verified optimum.
template<bool BF>
__global__ __launch_bounds__(512, 4) void vfx_mfma(
    const float* __restrict__ latent, const uint2* __restrict__ latbf,
    const int* __restrict__ raw_pos, const float* __restrict__ control,
    const ushort* __restrict__ wsrc,
    const float* __restrict__ b2, const float* __restrict__ b3,
    const float* __restrict__ b4, float* __restrict__ out)
{
    __shared__ ushort wl[WSTOT];            // 61,440 B -> 2 blocks/CU (16 waves)
    const int tid = threadIdx.x;
    const int wave = tid >> 6, lane = tid & 63;
    const int lo = lane & 15, hi = lane >> 4;
    const int pixbase = blockIdx.x * 256 + wave * 32;

    {   // stage weights + both LUTs: 3840 uint4
        const uint4* src = (const uint4*)wsrc;
        uint4* dst = (uint4*)wl;
        #pragma unroll
        for (int it = 0; it < 8; ++it) {
            const int i = tid + it * 512;
            if (i < 3840) dst[i] = src[i];
        }
    }

    // ---- prefetch positional data + issue all latent gathers BEFORE barrier ----
    const int g0 = pixbase + lo, g1 = pixbase + 16 + lo;
    const int2 rp0 = ((const int2*)raw_pos)[g0];
    const int2 rp1 = ((const int2*)raw_pos)[g1];
    const float2 cf0 = ((const float2*)control)[g0];
    const float2 cf1 = ((const float2*)control)[g1];

    const int na = 2 * hi, nbb = 2 * hi + 1;
    const int2 cA0 = nbc(rp0, na), cB0 = nbc(rp0, nbb);
    const int2 cA1 = nbc(rp1, na), cB1 = nbc(rp1, nbb);
    const int2 c80 = nbc(rp0, 8),  c81 = nbc(rp1, 8);

    uint2 lA0, lB0, lA1, lB1, l80, l81;
    if (BF) {
        lA0 = latbf[(cA0.y << 10) + cA0.x]; lB0 = latbf[(cB0.y << 10) + cB0.x];
        lA1 = latbf[(cA1.y << 10) + cA1.x]; lB1 = latbf[(cB1.y << 10) + cB1.x];
        if (hi == 0) { l80 = latbf[(c80.y << 10) + c80.x]; l81 = latbf[(c81.y << 10) + c81.x]; }
    } else {
        const float4* lf = (const float4*)latent;
        float4 a;
        a = lf[(cA0.y << 10) + cA0.x]; lA0 = make_uint2(pack2(a.x, a.y), pack2(a.z, a.w));
        a = lf[(cB0.y << 10) + cB0.x]; lB0 = make_uint2(pack2(a.x, a.y), pack2(a.z, a.w));
        a = lf[(cA1.y << 10) + cA1.x]; lA1 = make_uint2(pack2(a.x, a.y), pack2(a.z, a.w));
        a = lf[(cB1.y << 10) + cB1.x]; lB1 = make_uint2(pack2(a.x, a.y), pack2(a.z, a.w));
        if (hi == 0) {
            a = lf[(c80.y << 10) + c80.x]; l80 = make_uint2(pack2(a.x, a.y), pack2(a.z, a.w));
            a = lf[(c81.y << 10) + c81.x]; l81 = make_uint2(pack2(a.x, a.y), pack2(a.z, a.w));
        }
    }

    __syncthreads();   // LDS image ready (gather latency hid under staging)
    const ushort* glut = wl + GLUT_OFF;
    const uint*   slut = (const uint*)(wl + SLUT_OFF);

    // ---- assemble L1 B-fragments in registers (permuted feature order) ----
    short8 bX[2][4];
    {
        auto mk = [&](int2 c, uint2 lat, uint& s2u) -> short8 {
            const uint sx = slut[c.x], sy = slut[c.y];
            s2u = (sx >> 16) | (sy & 0xffff0000u);
            union { short8 s; uint u[4]; } o;
            o.u[0] = lat.x; o.u[1] = lat.y;
            o.u[2] = pack2((float)c.x * (1.0f / IMG), (float)c.y * (1.0f / IMG));
            o.u[3] = (sx & 0xffffu) | (sy << 16);
            return o.s;
        };
        uint s2a0, s2b0, s2a1, s2b1;
        bX[0][0] = mk(cA0, lA0, s2a0);
        bX[0][1] = mk(cB0, lB0, s2b0);
        bX[1][0] = mk(cA1, lA1, s2a1);
        bX[1][1] = mk(cB1, lB1, s2b1);
        const uint upc0 = pack2(cf0.x, cf0.y), upc1 = pack2(cf1.x, cf1.y);
        union { short8 s; uint u[4]; } t;
        t.u[0] = s2a0; t.u[1] = upc0; t.u[2] = s2b0; t.u[3] = upc0; bX[0][2] = t.s;
        t.u[0] = s2a1; t.u[1] = upc1; t.u[2] = s2b1; t.u[3] = upc1; bX[1][2] = t.s;
        if (hi == 0) {          // S1 frag of neighbor 8
            uint d0, d1;
            bX[0][3] = mk(c80, l80, d0);
            bX[1][3] = mk(c81, l81, d1);
        } else if (hi == 1) {   // [s2(nb8), ctrl, 1.0(bias), 0...]
            union { short8 s; uint u[4]; } o;
            o.u[0] = (slut[c80.x] >> 16) | (slut[c80.y] & 0xffff0000u);
            o.u[1] = upc0; o.u[2] = 0x3f80u; o.u[3] = 0u;
            bX[0][3] = o.s;
            o.u[0] = (slut[c81.x] >> 16) | (slut[c81.y] & 0xffff0000u);
            o.u[1] = upc1;
            bX[1][3] = o.s;
        } else {
            union { short8 s; uint u[4]; } z;
            z.u[0] = 0u; z.u[1] = 0u; z.u[2] = 0u; z.u[3] = 0u;
            bX[0][3] = z.s; bX[1][3] = z.s;
        }
    }

    short8 h1[2][2], h2[2][4], h3[2][2];
    mlayer_pf<4, 2, false>(bX, h1, wl + A1_OFF, nullptr, glut, lo, hi);  // 128 -> 64
    mlayer_pf<2, 4, true >(h1, h2, wl + A2_OFF, b2, glut, lo, hi);       // 64  -> 128
    mlayer_pf<4, 2, true >(h2, h3, wl + A3_OFF, b3, glut, lo, hi);       // 128 -> 64

    // ---- L4: 64 -> 4 (m-padded 16), sigmoid, float4 store ----
    {
        float4 bv = {0.f, 0.f, 0.f, 0.f};
        if (hi == 0) bv = *(const float4*)b4;
        f32x4 acc0 = {bv.x, bv.y, bv.z, bv.w};
        f32x4 acc1 = acc0;
        #pragma unroll
        for (int ks = 0; ks < 2; ++ks) {
            const short8 a = *(const short8*)&wl[A4_OFF + (ks * 512) + (hi * 16 + lo) * 8];
            acc0 = __builtin_amdgcn_mfma_f32_16x16x32_bf16(a, h3[0][ks], acc0, 0, 0, 0);
            acc1 = __builtin_amdgcn_mfma_f32_16x16x32_bf16(a, h3[1][ks], acc1, 0, 0, 0);
        }
        if (hi == 0) {   // rows 0..3 = the 4 outputs, col = pixel lo
            float4 o;
            o.x = sig_fast(acc0[0]); o.y = sig_fast(acc0[1]);
            o.z = sig_fast(acc0[2]); o.w = sig_fast(acc0[3]);
            *(float4*)&out[(pixbase + lo) * 4] = o;
            o.x = sig_fast(acc1[0]); o.y = sig_fast(acc1[1]);
            o.z = sig_fast(acc1[2]); o.w = sig_fast(acc1[3]);
            *(float4*)&out[(pixbase + 16 + lo) * 4] = o;
        }
    }
}

extern "C" void kernel_launch(void* const* d_in, const int* in_sizes, int n_in,
                              void* d_out, int out_size, void* d_ws, size_t ws_size,
                              hipStream_t stream) {
    const float* latent  = (const float*)d_in[0];
    const int*   raw_pos = (const int*)  d_in[1];
    const float* control = (const float*)d_in[2];
    const float* W1 = (const float*)d_in[3];
    const float* b1 = (const float*)d_in[4];
    const float* W2 = (const float*)d_in[5];
    const float* b2 = (const float*)d_in[6];
    const float* W3 = (const float*)d_in[7];
    const float* b3 = (const float*)d_in[8];
    const float* W4 = (const float*)d_in[9];
    const float* b4 = (const float*)d_in[10];
    float* out = (float*)d_out;
    ushort* ws = (ushort*)d_ws;

    const size_t need = (size_t)LATBF_BYTEOFF + (size_t)NPIXTOT * 8;
    const bool use_bf = ws_size >= need;
    dim3 grid(NPIXTOT / 256);   // 8192 blocks x 512 threads, 256 pixels/block

    if (use_bf) {
        ushort* latbf = (ushort*)((char*)d_ws + LATBF_BYTEOFF);
        prep_all<<<dim3(NPIXTOT / 256), dim3(256), 0, stream>>>(
            W1, b1, W2, W3, W4, latent, ws, latbf);
        vfx_mfma<true><<<grid, dim3(512), 0, stream>>>(
            latent, (const uint2*)latbf, raw_pos, control, ws, b2, b3, b4, out);
    } else {
        prep_all<<<dim3(NPIXTOT / 256), dim3(256), 0, stream>>>(
            W1, b1, W2, W3, W4, latent, ws, (ushort*)d_ws + WSTOT);  // latbf unused path
        vfx_mfma<false><<<grid, dim3(512), 0, stream>>>(
            latent, nullptr, raw_pos, control, ws, b2, b3, b4, out);
    }
}